// Round 1
// baseline (4438.589 us; speedup 1.0000x reference)
//
#include <hip/hip_runtime.h>
#include <hip/hip_bf16.h>

// Problem dims
constexpr int NB = 32, NS = 512, NE = 256, NC = 128, NHD = 256, NG = 1024, NT = 16, NH = 512;
constexpr int NV = 50000;

// ---------------- helpers ----------------
__device__ __forceinline__ unsigned short f2bf(float f) {
    unsigned u = __float_as_uint(f);
    u += 0x7fffu + ((u >> 16) & 1u);
    return (unsigned short)(u >> 16);
}
__device__ __forceinline__ float bf2f(unsigned short s) {
    return __uint_as_float(((unsigned)s) << 16);
}
__device__ __forceinline__ float sigm(float x) { return 1.f / (1.f + __expf(-x)); }
__device__ __forceinline__ float tanh_fast(float x) {
    float xc = fminf(fmaxf(x, -15.f), 15.f);
    float t = __expf(2.f * xc);
    return (t - 1.f) / (t + 1.f);
}

// ---------------- prep: weight transposes ----------------
// wT[e3][c] = conv_w[c][e3]   (e3 = e*3+k, 768x128)
__global__ void k_prep_convw(const float* __restrict__ w, float* __restrict__ wT) {
    int i = blockIdx.x * 256 + threadIdx.x;
    if (i >= 768 * 128) return;
    int e3 = i >> 7, c = i & 127;
    wT[i] = w[c * 768 + e3];
}

// whhT[d][(k*256+j)*4+g] = whh_d[(g*256+j)*256+k]  (f32)
__global__ void k_prep_whh(const float* __restrict__ whh_f, const float* __restrict__ whh_b,
                           float* __restrict__ whhT) {
    int d = blockIdx.y;
    const float* src = d ? whh_b : whh_f;
    int i = blockIdx.x * 256 + threadIdx.x;
    if (i >= NHD * NG) return;
    int g = i & 3, j = (i >> 2) & 255, k = i >> 10;
    whhT[(size_t)d * NHD * NG + i] = src[(g * 256 + j) * 256 + k];
}

// wihT[d][(e*256+j)*4+g] = wih_d[(g*256+j)*128+e]  (f32)
__global__ void k_prep_wih(const float* __restrict__ wih_f, const float* __restrict__ wih_b,
                           float* __restrict__ wihT) {
    int d = blockIdx.y;
    const float* src = d ? wih_b : wih_f;
    int i = blockIdx.x * 256 + threadIdx.x;
    if (i >= NC * NG) return;
    int g = i & 3, j = (i >> 2) & 255, e = i >> 10;
    wihT[(size_t)d * NC * NG + i] = src[(g * 256 + j) * 128 + e];
}

// bias2[d][j*4+g] = bih[g*256+j] + bhh[g*256+j]
__global__ void k_prep_bias(const float* __restrict__ bih_f, const float* __restrict__ bhh_f,
                            const float* __restrict__ bih_b, const float* __restrict__ bhh_b,
                            float* __restrict__ bias2) {
    int d = blockIdx.y;
    const float* bi = d ? bih_b : bih_f;
    const float* bh = d ? bhh_b : bhh_f;
    int i = blockIdx.x * 256 + threadIdx.x;
    if (i >= NG) return;
    int g = i & 3, j = i >> 2;
    bias2[(size_t)d * NG + i] = bi[g * 256 + j] + bh[g * 256 + j];
}

// ---------------- embedding + conv1d(k=3,pad=1) + relu ----------------
// feat[b][s][c], block = (s_tile of 8, b), 128 threads (thread = channel)
__global__ __launch_bounds__(128) void k_conv(const int* __restrict__ x,
                                              const float* __restrict__ table,
                                              const float* __restrict__ wT,
                                              const float* __restrict__ conv_b,
                                              float* __restrict__ feat) {
    int b = blockIdx.y;
    int s0 = blockIdx.x * 8;
    int c = threadIdx.x;
    __shared__ float win[10][NE];
    for (int i = 0; i < 10; ++i) {
        int s = s0 - 1 + i;
        if (s < 0 || s >= NS) {
            for (int e = c; e < NE; e += 128) win[i][e] = 0.f;
        } else {
            int tok = x[b * NS + s];
            const float* row = table + (size_t)tok * NE;
            for (int e = c; e < NE; e += 128) win[i][e] = row[e];
        }
    }
    __syncthreads();
    float acc[8];
    float bc = conv_b[c];
#pragma unroll
    for (int p = 0; p < 8; ++p) acc[p] = bc;
    for (int e = 0; e < NE; ++e) {
        float r[10];
#pragma unroll
        for (int i = 0; i < 10; ++i) r[i] = win[i][e];
#pragma unroll
        for (int k = 0; k < 3; ++k) {
            float wv = wT[(e * 3 + k) * NC + c];
#pragma unroll
            for (int p = 0; p < 8; ++p) acc[p] += wv * r[p + k];
        }
    }
#pragma unroll
    for (int p = 0; p < 8; ++p) {
        feat[((size_t)b * NS + s0 + p) * NC + c] = fmaxf(acc[p], 0.f);
    }
}

// ---------------- input-side gates: xg[d][(s*B+b)*256+j]*4+g  (bf16) ----------------
// block = (pair tile of 8, dir), 256 threads (thread = cell j)
__global__ __launch_bounds__(256) void k_xgate(const float* __restrict__ feat,
                                               const float* __restrict__ wihT,
                                               const float* __restrict__ bias2,
                                               unsigned short* __restrict__ xg) {
    int d = blockIdx.y;
    int p0 = blockIdx.x * 8;  // pair idx = s*NB + b
    int j = threadIdx.x;
    __shared__ float fv[8][NC];
    for (int i = threadIdx.x; i < 8 * NC; i += 256) {
        int p = i >> 7, e = i & 127;
        int idx = p0 + p;
        int s = idx >> 5, b = idx & 31;
        fv[p][e] = feat[((size_t)b * NS + s) * NC + e];
    }
    __syncthreads();
    const float* W = wihT + (size_t)d * NC * NG;
    float b0 = bias2[(size_t)d * NG + j * 4 + 0];
    float b1 = bias2[(size_t)d * NG + j * 4 + 1];
    float b2 = bias2[(size_t)d * NG + j * 4 + 2];
    float b3 = bias2[(size_t)d * NG + j * 4 + 3];
    float acc[8][4];
#pragma unroll
    for (int p = 0; p < 8; ++p) {
        acc[p][0] = b0; acc[p][1] = b1; acc[p][2] = b2; acc[p][3] = b3;
    }
    for (int e = 0; e < NC; ++e) {
        float4 w4 = *(const float4*)(W + ((size_t)e * 256 + j) * 4);
#pragma unroll
        for (int p = 0; p < 8; ++p) {
            float fe = fv[p][e];
            acc[p][0] += fe * w4.x;
            acc[p][1] += fe * w4.y;
            acc[p][2] += fe * w4.z;
            acc[p][3] += fe * w4.w;
        }
    }
#pragma unroll
    for (int p = 0; p < 8; ++p) {
        ushort4 o;
        o.x = f2bf(acc[p][0]); o.y = f2bf(acc[p][1]);
        o.z = f2bf(acc[p][2]); o.w = f2bf(acc[p][3]);
        unsigned short* dst = xg + (size_t)d * NS * NB * NG + ((size_t)(p0 + p) * 256 + j) * 4;
        *(ushort4*)dst = o;
    }
}

// ---------------- LSTM recurrence: block = (dir, batch), thread = cell ----------------
__global__ __launch_bounds__(256) void k_lstm(const float* __restrict__ whhT,
                                              const unsigned short* __restrict__ xg,
                                              float* __restrict__ hcat) {
    int blk = blockIdx.x;
    int d = blk >> 5, b = blk & 31;
    int j = threadIdx.x;
    __shared__ float h_lds[NHD];
    h_lds[j] = 0.f;
    float cst = 0.f;
    const float* W = whhT + (size_t)d * NHD * NG;
    const unsigned short* XG = xg + (size_t)d * NS * NB * NG;
    __syncthreads();
    for (int step = 0; step < NS; ++step) {
        int s = d ? (NS - 1 - step) : step;
        ushort4 xv = *(const ushort4*)(XG + ((size_t)(s * NB + b) * 256 + j) * 4);
        float a0 = bf2f(xv.x), a1 = bf2f(xv.y), a2 = bf2f(xv.z), a3 = bf2f(xv.w);
#pragma unroll 8
        for (int k = 0; k < NHD; ++k) {
            float hk = h_lds[k];
            float4 w4 = *(const float4*)(W + ((size_t)k * 256 + j) * 4);
            a0 += hk * w4.x;
            a1 += hk * w4.y;
            a2 += hk * w4.z;
            a3 += hk * w4.w;
        }
        float ig = sigm(a0);
        float fg = sigm(a1);
        float gg = tanh_fast(a2);
        float og = sigm(a3);
        cst = fg * cst + ig * gg;
        float h = og * tanh_fast(cst);
        hcat[(size_t)(s * NB + b) * NH + d * NHD + j] = h;
        __syncthreads();
        h_lds[j] = h;
        __syncthreads();
    }
}

// ---------------- FC to emissions: em[s][b][t] ----------------
__global__ __launch_bounds__(256) void k_fc(const float* __restrict__ hcat,
                                            const float* __restrict__ fc_w,
                                            const float* __restrict__ fc_b,
                                            float* __restrict__ em) {
    int p0 = blockIdx.x * 16;  // 16 pairs (s*NB+b linear)
    __shared__ float hv[16][NH];
    for (int i = threadIdx.x; i < 16 * NH; i += 256) {
        int p = i >> 9, hh = i & 511;
        hv[p][hh] = hcat[(size_t)(p0 + p) * NH + hh];
    }
    __syncthreads();
    int p = threadIdx.x >> 4, t = threadIdx.x & 15;
    const float* fw = fc_w + t * NH;
    float acc = fc_b[t];
#pragma unroll 8
    for (int hh = 0; hh < NH; ++hh) acc += hv[p][hh] * fw[hh];
    em[(size_t)(p0 + p) * NT + t] = acc;
}

// ---------------- CRF NLL per batch ----------------
__global__ __launch_bounds__(64) void k_crf(const float* __restrict__ em,
                                            const int* __restrict__ tags,
                                            const int* __restrict__ mask,
                                            const float* __restrict__ start_t,
                                            const float* __restrict__ end_t,
                                            const float* __restrict__ trans,
                                            float* __restrict__ res) {
    int b = blockIdx.x;
    int tid = threadIdx.x;
    __shared__ float tr[NT * NT];
    __shared__ float alpha[NT];
    __shared__ float sc_sh;
    for (int i = tid; i < NT * NT; i += 64) tr[i] = trans[i];
    // gold-path score (parallel over s) + mask sum
    float part = 0.f, msum = 0.f;
    for (int s = tid; s < NS; s += 64) msum += (float)mask[b * NS + s];
    for (int s = 1 + tid; s < NS; s += 64) {
        int pv = tags[b * NS + s - 1], cu = tags[b * NS + s];
        float mm = (float)mask[b * NS + s];
        part += (tr[pv * NT + cu] + em[((size_t)s * NB + b) * NT + cu]) * mm;
    }
#pragma unroll
    for (int o = 32; o > 0; o >>= 1) {
        part += __shfl_down(part, o);
        msum += __shfl_down(msum, o);
    }
    if (tid == 0) {
        int t0 = tags[b * NS];
        int send = (int)msum - 1;
        sc_sh = start_t[t0] + em[(size_t)b * NT + t0] + part + end_t[tags[b * NS + send]];
    }
    // log-partition (sequential forward algorithm)
    if (tid < NT) alpha[tid] = start_t[tid] + em[(size_t)b * NT + tid];
    __syncthreads();
    for (int s = 1; s < NS; ++s) {
        float nv = 0.f;
        if (tid < NT) {
            float mx = -1e30f;
#pragma unroll
            for (int t = 0; t < NT; ++t) mx = fmaxf(mx, alpha[t] + tr[t * NT + tid]);
            float sum = 0.f;
#pragma unroll
            for (int t = 0; t < NT; ++t) sum += __expf(alpha[t] + tr[t * NT + tid] - mx);
            nv = mx + __logf(sum) + em[((size_t)s * NB + b) * NT + tid];
            float mm = (float)mask[b * NS + s];
            nv = (mm > 0.f) ? nv : alpha[tid];
        }
        __syncthreads();
        if (tid < NT) alpha[tid] = nv;
        __syncthreads();
    }
    if (tid == 0) {
        float mx = -1e30f;
        for (int t = 0; t < NT; ++t) mx = fmaxf(mx, alpha[t] + end_t[t]);
        float sum = 0.f;
        for (int t = 0; t < NT; ++t) sum += __expf(alpha[t] + end_t[t] - mx);
        res[b] = sc_sh - (mx + __logf(sum));
    }
}

__global__ void k_final(const float* __restrict__ res, float* __restrict__ out) {
    int tid = threadIdx.x;
    float v = (tid < NB) ? res[tid] : 0.f;
#pragma unroll
    for (int o = 32; o > 0; o >>= 1) v += __shfl_down(v, o);
    if (tid == 0) out[0] = -v / NB;
}

// ---------------- workspace layout ----------------
constexpr size_t SZ_FEAT = (size_t)NB * NS * NC * 4;     // 8 MB
constexpr size_t SZ_WT   = (size_t)768 * 128 * 4;        // 384 KB
constexpr size_t SZ_WHHT = (size_t)2 * NHD * NG * 4;     // 2 MB
constexpr size_t SZ_WIHT = (size_t)2 * NC * NG * 4;      // 1 MB
constexpr size_t SZ_BIAS = (size_t)2 * NG * 4;           // 8 KB
constexpr size_t SZ_XG   = (size_t)2 * NS * NB * NG * 2; // 64 MB (bf16)
constexpr size_t SZ_HCAT = (size_t)NS * NB * NH * 4;     // 32 MB
constexpr size_t SZ_EM   = (size_t)NS * NB * NT * 4;     // 1 MB

constexpr size_t OFF_FEAT = 0;
constexpr size_t OFF_WT   = OFF_FEAT + SZ_FEAT;
constexpr size_t OFF_WHHT = OFF_WT + SZ_WT;
constexpr size_t OFF_WIHT = OFF_WHHT + SZ_WHHT;
constexpr size_t OFF_BIAS = OFF_WIHT + SZ_WIHT;
constexpr size_t OFF_XG   = OFF_BIAS + SZ_BIAS;
constexpr size_t OFF_HCAT = OFF_XG + SZ_XG;
constexpr size_t OFF_EM   = OFF_HCAT + SZ_HCAT;
constexpr size_t OFF_RES  = OFF_EM + SZ_EM;

extern "C" void kernel_launch(void* const* d_in, const int* in_sizes, int n_in,
                              void* d_out, int out_size, void* d_ws, size_t ws_size,
                              hipStream_t stream) {
    const int* x        = (const int*)d_in[0];
    const int* mask     = (const int*)d_in[1];
    const int* tags     = (const int*)d_in[2];
    const float* table  = (const float*)d_in[3];
    const float* conv_w = (const float*)d_in[4];
    const float* conv_b = (const float*)d_in[5];
    const float* wih_f  = (const float*)d_in[6];
    const float* whh_f  = (const float*)d_in[7];
    const float* bih_f  = (const float*)d_in[8];
    const float* bhh_f  = (const float*)d_in[9];
    const float* wih_b  = (const float*)d_in[10];
    const float* whh_b  = (const float*)d_in[11];
    const float* bih_b  = (const float*)d_in[12];
    const float* bhh_b  = (const float*)d_in[13];
    const float* fc_w   = (const float*)d_in[14];
    const float* fc_b   = (const float*)d_in[15];
    const float* start_t = (const float*)d_in[16];
    const float* end_t  = (const float*)d_in[17];
    const float* trans  = (const float*)d_in[18];

    char* ws = (char*)d_ws;
    float* feat = (float*)(ws + OFF_FEAT);
    float* wT   = (float*)(ws + OFF_WT);
    float* whhT = (float*)(ws + OFF_WHHT);
    float* wihT = (float*)(ws + OFF_WIHT);
    float* bias2 = (float*)(ws + OFF_BIAS);
    unsigned short* xg = (unsigned short*)(ws + OFF_XG);
    float* hcat = (float*)(ws + OFF_HCAT);
    float* em   = (float*)(ws + OFF_EM);
    float* res  = (float*)(ws + OFF_RES);

    k_prep_convw<<<dim3(384), 256, 0, stream>>>(conv_w, wT);
    k_prep_whh<<<dim3(1024, 2), 256, 0, stream>>>(whh_f, whh_b, whhT);
    k_prep_wih<<<dim3(512, 2), 256, 0, stream>>>(wih_f, wih_b, wihT);
    k_prep_bias<<<dim3(4, 2), 256, 0, stream>>>(bih_f, bhh_f, bih_b, bhh_b, bias2);
    k_conv<<<dim3(NS / 8, NB), 128, 0, stream>>>(x, table, wT, conv_b, feat);
    k_xgate<<<dim3(NS * NB / 8, 2), 256, 0, stream>>>(feat, wihT, bias2, xg);
    k_lstm<<<dim3(64), 256, 0, stream>>>(whhT, xg, hcat);
    k_fc<<<dim3(NS * NB / 16), 256, 0, stream>>>(hcat, fc_w, fc_b, em);
    k_crf<<<dim3(NB), 64, 0, stream>>>(em, tags, mask, start_t, end_t, trans, res);
    k_final<<<dim3(1), 64, 0, stream>>>(res, (float*)d_out);
}

// Round 2
// 2660.931 us; speedup vs baseline: 1.6681x; 1.6681x over previous
//
#include <hip/hip_runtime.h>
#include <hip/hip_bf16.h>

// Problem dims
constexpr int NB = 32, NS = 512, NE = 256, NC = 128, NHD = 256, NG = 1024, NT = 16, NH = 512;

typedef _Float16 h2 __attribute__((ext_vector_type(2)));

// ---------------- helpers ----------------
__device__ __forceinline__ unsigned short f2bf(float f) {
    unsigned u = __float_as_uint(f);
    u += 0x7fffu + ((u >> 16) & 1u);
    return (unsigned short)(u >> 16);
}
__device__ __forceinline__ float bf2f(unsigned short s) {
    return __uint_as_float(((unsigned)s) << 16);
}
__device__ __forceinline__ float sigm(float x) { return 1.f / (1.f + __expf(-x)); }
__device__ __forceinline__ float tanh_fast(float x) {
    float xc = fminf(fmaxf(x, -15.f), 15.f);
    float t = __expf(2.f * xc);
    return (t - 1.f) / (t + 1.f);
}
__device__ __forceinline__ float dot2h(unsigned w, h2 hh, float acc) {
    h2 wv = __builtin_bit_cast(h2, w);
#if __has_builtin(__builtin_amdgcn_fdot2)
    return __builtin_amdgcn_fdot2(wv, hh, acc, false);
#else
    return acc + (float)wv.x * (float)hh.x + (float)wv.y * (float)hh.y;
#endif
}

// ---------------- prep: weight transposes ----------------
// wT[e3][c] = conv_w[c][e3]   (e3 = e*3+k, 768x128)
__global__ void k_prep_convw(const float* __restrict__ w, float* __restrict__ wT) {
    int i = blockIdx.x * 256 + threadIdx.x;
    if (i >= 768 * 128) return;
    int e3 = i >> 7, c = i & 127;
    wT[i] = w[c * 768 + e3];
}

// f16-pair layout: whhH[d][k2*1024 + j*4 + g] = half2{ whh[g*256+j][2k2], whh[g*256+j][2k2+1] }
__global__ void k_prep_whh_h(const float* __restrict__ whh_f, const float* __restrict__ whh_b,
                             unsigned* __restrict__ whhH) {
    int d = blockIdx.y;
    const float* src = d ? whh_b : whh_f;
    int i = blockIdx.x * 256 + threadIdx.x;
    if (i >= (NHD / 2) * NG) return;
    int g = i & 3, j = (i >> 2) & 255, k2 = i >> 10;
    float v0 = src[(g * 256 + j) * 256 + 2 * k2];
    float v1 = src[(g * 256 + j) * 256 + 2 * k2 + 1];
    h2 p;
    p.x = (_Float16)v0;
    p.y = (_Float16)v1;
    whhH[(size_t)d * ((NHD / 2) * NG) + i] = __builtin_bit_cast(unsigned, p);
}

// wihT[d][(e*256+j)*4+g] = wih_d[(g*256+j)*128+e]  (f32)
__global__ void k_prep_wih(const float* __restrict__ wih_f, const float* __restrict__ wih_b,
                           float* __restrict__ wihT) {
    int d = blockIdx.y;
    const float* src = d ? wih_b : wih_f;
    int i = blockIdx.x * 256 + threadIdx.x;
    if (i >= NC * NG) return;
    int g = i & 3, j = (i >> 2) & 255, e = i >> 10;
    wihT[(size_t)d * NC * NG + i] = src[(g * 256 + j) * 128 + e];
}

// bias2[d][j*4+g] = bih[g*256+j] + bhh[g*256+j]
__global__ void k_prep_bias(const float* __restrict__ bih_f, const float* __restrict__ bhh_f,
                            const float* __restrict__ bih_b, const float* __restrict__ bhh_b,
                            float* __restrict__ bias2) {
    int d = blockIdx.y;
    const float* bi = d ? bih_b : bih_f;
    const float* bh = d ? bhh_b : bhh_f;
    int i = blockIdx.x * 256 + threadIdx.x;
    if (i >= NG) return;
    int g = i & 3, j = i >> 2;
    bias2[(size_t)d * NG + i] = bi[g * 256 + j] + bh[g * 256 + j];
}

// ---------------- embedding + conv1d(k=3,pad=1) + relu ----------------
__global__ __launch_bounds__(128) void k_conv(const int* __restrict__ x,
                                              const float* __restrict__ table,
                                              const float* __restrict__ wT,
                                              const float* __restrict__ conv_b,
                                              float* __restrict__ feat) {
    int b = blockIdx.y;
    int s0 = blockIdx.x * 8;
    int c = threadIdx.x;
    __shared__ float win[10][NE];
    for (int i = 0; i < 10; ++i) {
        int s = s0 - 1 + i;
        if (s < 0 || s >= NS) {
            for (int e = c; e < NE; e += 128) win[i][e] = 0.f;
        } else {
            int tok = x[b * NS + s];
            const float* row = table + (size_t)tok * NE;
            for (int e = c; e < NE; e += 128) win[i][e] = row[e];
        }
    }
    __syncthreads();
    float acc[8];
    float bc = conv_b[c];
#pragma unroll
    for (int p = 0; p < 8; ++p) acc[p] = bc;
    for (int e = 0; e < NE; ++e) {
        float r[10];
#pragma unroll
        for (int i = 0; i < 10; ++i) r[i] = win[i][e];
#pragma unroll
        for (int k = 0; k < 3; ++k) {
            float wv = wT[(e * 3 + k) * NC + c];
#pragma unroll
            for (int p = 0; p < 8; ++p) acc[p] += wv * r[p + k];
        }
    }
#pragma unroll
    for (int p = 0; p < 8; ++p) {
        feat[((size_t)b * NS + s0 + p) * NC + c] = fmaxf(acc[p], 0.f);
    }
}

// ---------------- input-side gates: xg[d][(s*B+b)*256+j]*4+g  (bf16) ----------------
__global__ __launch_bounds__(256) void k_xgate(const float* __restrict__ feat,
                                               const float* __restrict__ wihT,
                                               const float* __restrict__ bias2,
                                               unsigned short* __restrict__ xg) {
    int d = blockIdx.y;
    int p0 = blockIdx.x * 8;  // pair idx = s*NB + b
    int j = threadIdx.x;
    __shared__ float fv[8][NC];
    for (int i = threadIdx.x; i < 8 * NC; i += 256) {
        int p = i >> 7, e = i & 127;
        int idx = p0 + p;
        int s = idx >> 5, b = idx & 31;
        fv[p][e] = feat[((size_t)b * NS + s) * NC + e];
    }
    __syncthreads();
    const float* W = wihT + (size_t)d * NC * NG;
    float b0 = bias2[(size_t)d * NG + j * 4 + 0];
    float b1 = bias2[(size_t)d * NG + j * 4 + 1];
    float b2 = bias2[(size_t)d * NG + j * 4 + 2];
    float b3 = bias2[(size_t)d * NG + j * 4 + 3];
    float acc[8][4];
#pragma unroll
    for (int p = 0; p < 8; ++p) {
        acc[p][0] = b0; acc[p][1] = b1; acc[p][2] = b2; acc[p][3] = b3;
    }
    for (int e = 0; e < NC; ++e) {
        float4 w4 = *(const float4*)(W + ((size_t)e * 256 + j) * 4);
#pragma unroll
        for (int p = 0; p < 8; ++p) {
            float fe = fv[p][e];
            acc[p][0] += fe * w4.x;
            acc[p][1] += fe * w4.y;
            acc[p][2] += fe * w4.z;
            acc[p][3] += fe * w4.w;
        }
    }
#pragma unroll
    for (int p = 0; p < 8; ++p) {
        ushort4 o;
        o.x = f2bf(acc[p][0]); o.y = f2bf(acc[p][1]);
        o.z = f2bf(acc[p][2]); o.w = f2bf(acc[p][3]);
        unsigned short* dst = xg + (size_t)d * NS * NB * NG + ((size_t)(p0 + p) * 256 + j) * 4;
        *(ushort4*)dst = o;
    }
}

// ---------------- LSTM recurrence: block = (dir, batch), thread = cell ----------------
// f16 weights consumed via v_dot2_f32_f16; h double-buffered in LDS as f16.
__global__ __launch_bounds__(256) void k_lstm(const unsigned* __restrict__ whhH,
                                              const unsigned short* __restrict__ xg,
                                              float* __restrict__ hcat) {
    int blk = blockIdx.x;
    int d = blk >> 5, b = blk & 31;
    int j = threadIdx.x;
    __shared__ _Float16 h16[2][NHD];
    h16[0][j] = (_Float16)0.f;
    float cst = 0.f;
    const uint4* W = (const uint4*)(whhH + (size_t)d * ((NHD / 2) * NG));
    const unsigned short* XG = xg + (size_t)d * NS * NB * NG;
    __syncthreads();
    int cur = 0;
    for (int step = 0; step < NS; ++step) {
        int s = d ? (NS - 1 - step) : step;
        ushort4 xv = *(const ushort4*)(XG + ((size_t)(s * NB + b) * 256 + j) * 4);
        float a0 = bf2f(xv.x), a1 = bf2f(xv.y), a2 = bf2f(xv.z), a3 = bf2f(xv.w);
        const h2* hp = (const h2*)h16[cur];
#pragma unroll 8
        for (int k2 = 0; k2 < NHD / 2; ++k2) {
            h2 hh = hp[k2];
            uint4 w = W[k2 * 256 + j];
            a0 = dot2h(w.x, hh, a0);
            a1 = dot2h(w.y, hh, a1);
            a2 = dot2h(w.z, hh, a2);
            a3 = dot2h(w.w, hh, a3);
        }
        float ig = sigm(a0);
        float fg = sigm(a1);
        float gg = tanh_fast(a2);
        float og = sigm(a3);
        cst = fg * cst + ig * gg;
        float h = og * tanh_fast(cst);
        hcat[(size_t)(s * NB + b) * NH + d * NHD + j] = h;
        h16[cur ^ 1][j] = (_Float16)h;
        __syncthreads();
        cur ^= 1;
    }
}

// ---------------- FC to emissions: em[s][b][t] ----------------
__global__ __launch_bounds__(256) void k_fc(const float* __restrict__ hcat,
                                            const float* __restrict__ fc_w,
                                            const float* __restrict__ fc_b,
                                            float* __restrict__ em) {
    int p0 = blockIdx.x * 16;  // 16 pairs (s*NB+b linear)
    __shared__ float hv[16][NH];
    for (int i = threadIdx.x; i < 16 * NH; i += 256) {
        int p = i >> 9, hh = i & 511;
        hv[p][hh] = hcat[(size_t)(p0 + p) * NH + hh];
    }
    __syncthreads();
    int p = threadIdx.x >> 4, t = threadIdx.x & 15;
    const float* fw = fc_w + t * NH;
    float acc = fc_b[t];
#pragma unroll 8
    for (int hh = 0; hh < NH; ++hh) acc += hv[p][hh] * fw[hh];
    em[(size_t)(p0 + p) * NT + t] = acc;
}

// ---------------- CRF NLL per batch (emissions staged in LDS) ----------------
__global__ __launch_bounds__(64) void k_crf(const float* __restrict__ em,
                                            const int* __restrict__ tags,
                                            const int* __restrict__ mask,
                                            const float* __restrict__ start_t,
                                            const float* __restrict__ end_t,
                                            const float* __restrict__ trans,
                                            float* __restrict__ res) {
    int b = blockIdx.x;
    int tid = threadIdx.x;
    __shared__ float em_sh[NS * NT];   // 32 KB
    __shared__ float tr[NT * NT];
    __shared__ float alpha[NT];
    __shared__ float sc_sh;
    for (int i = tid; i < NT * NT; i += 64) tr[i] = trans[i];
    // stage this batch's emissions into LDS
    for (int i = tid; i < NS * NT; i += 64) {
        int s = i >> 4, t = i & 15;
        em_sh[i] = em[((size_t)s * NB + b) * NT + t];
    }
    __syncthreads();
    // gold-path score (parallel over s) + mask sum
    float part = 0.f, msum = 0.f;
    for (int s = tid; s < NS; s += 64) msum += (float)mask[b * NS + s];
    for (int s = 1 + tid; s < NS; s += 64) {
        int pv = tags[b * NS + s - 1], cu = tags[b * NS + s];
        float mm = (float)mask[b * NS + s];
        part += (tr[pv * NT + cu] + em_sh[s * NT + cu]) * mm;
    }
#pragma unroll
    for (int o = 32; o > 0; o >>= 1) {
        part += __shfl_down(part, o);
        msum += __shfl_down(msum, o);
    }
    if (tid == 0) {
        int t0 = tags[b * NS];
        int send = (int)msum - 1;
        sc_sh = start_t[t0] + em_sh[t0] + part + end_t[tags[b * NS + send]];
    }
    // log-partition (sequential forward algorithm), all from LDS
    if (tid < NT) alpha[tid] = start_t[tid] + em_sh[tid];
    __syncthreads();
    for (int s = 1; s < NS; ++s) {
        float nv = 0.f;
        if (tid < NT) {
            float mx = -1e30f;
#pragma unroll
            for (int t = 0; t < NT; ++t) mx = fmaxf(mx, alpha[t] + tr[t * NT + tid]);
            float sum = 0.f;
#pragma unroll
            for (int t = 0; t < NT; ++t) sum += __expf(alpha[t] + tr[t * NT + tid] - mx);
            nv = mx + __logf(sum) + em_sh[s * NT + tid];
            float mm = (float)mask[b * NS + s];
            nv = (mm > 0.f) ? nv : alpha[tid];
        }
        __syncthreads();
        if (tid < NT) alpha[tid] = nv;
        __syncthreads();
    }
    if (tid == 0) {
        float mx = -1e30f;
        for (int t = 0; t < NT; ++t) mx = fmaxf(mx, alpha[t] + end_t[t]);
        float sum = 0.f;
        for (int t = 0; t < NT; ++t) sum += __expf(alpha[t] + end_t[t] - mx);
        res[b] = sc_sh - (mx + __logf(sum));
    }
}

__global__ void k_final(const float* __restrict__ res, float* __restrict__ out) {
    int tid = threadIdx.x;
    float v = (tid < NB) ? res[tid] : 0.f;
#pragma unroll
    for (int o = 32; o > 0; o >>= 1) v += __shfl_down(v, o);
    if (tid == 0) out[0] = -v / NB;
}

// ---------------- workspace layout ----------------
constexpr size_t SZ_FEAT = (size_t)NB * NS * NC * 4;     // 8 MB
constexpr size_t SZ_WT   = (size_t)768 * 128 * 4;        // 384 KB
constexpr size_t SZ_WHHH = (size_t)2 * (NHD / 2) * NG * 4; // 1 MB (f16 pairs as u32)
constexpr size_t SZ_WIHT = (size_t)2 * NC * NG * 4;      // 1 MB
constexpr size_t SZ_BIAS = (size_t)2 * NG * 4;           // 8 KB
constexpr size_t SZ_XG   = (size_t)2 * NS * NB * NG * 2; // 64 MB (bf16)
constexpr size_t SZ_HCAT = (size_t)NS * NB * NH * 4;     // 32 MB
constexpr size_t SZ_EM   = (size_t)NS * NB * NT * 4;     // 1 MB

constexpr size_t OFF_FEAT = 0;
constexpr size_t OFF_WT   = OFF_FEAT + SZ_FEAT;
constexpr size_t OFF_WHHH = OFF_WT + SZ_WT;
constexpr size_t OFF_WIHT = OFF_WHHH + SZ_WHHH;
constexpr size_t OFF_BIAS = OFF_WIHT + SZ_WIHT;
constexpr size_t OFF_XG   = OFF_BIAS + SZ_BIAS;
constexpr size_t OFF_HCAT = OFF_XG + SZ_XG;
constexpr size_t OFF_EM   = OFF_HCAT + SZ_HCAT;
constexpr size_t OFF_RES  = OFF_EM + SZ_EM;

extern "C" void kernel_launch(void* const* d_in, const int* in_sizes, int n_in,
                              void* d_out, int out_size, void* d_ws, size_t ws_size,
                              hipStream_t stream) {
    const int* x        = (const int*)d_in[0];
    const int* mask     = (const int*)d_in[1];
    const int* tags     = (const int*)d_in[2];
    const float* table  = (const float*)d_in[3];
    const float* conv_w = (const float*)d_in[4];
    const float* conv_b = (const float*)d_in[5];
    const float* wih_f  = (const float*)d_in[6];
    const float* whh_f  = (const float*)d_in[7];
    const float* bih_f  = (const float*)d_in[8];
    const float* bhh_f  = (const float*)d_in[9];
    const float* wih_b  = (const float*)d_in[10];
    const float* whh_b  = (const float*)d_in[11];
    const float* bih_b  = (const float*)d_in[12];
    const float* bhh_b  = (const float*)d_in[13];
    const float* fc_w   = (const float*)d_in[14];
    const float* fc_b   = (const float*)d_in[15];
    const float* start_t = (const float*)d_in[16];
    const float* end_t  = (const float*)d_in[17];
    const float* trans  = (const float*)d_in[18];

    char* ws = (char*)d_ws;
    float* feat = (float*)(ws + OFF_FEAT);
    float* wT   = (float*)(ws + OFF_WT);
    unsigned* whhH = (unsigned*)(ws + OFF_WHHH);
    float* wihT = (float*)(ws + OFF_WIHT);
    float* bias2 = (float*)(ws + OFF_BIAS);
    unsigned short* xg = (unsigned short*)(ws + OFF_XG);
    float* hcat = (float*)(ws + OFF_HCAT);
    float* em   = (float*)(ws + OFF_EM);
    float* res  = (float*)(ws + OFF_RES);

    k_prep_convw<<<dim3(384), 256, 0, stream>>>(conv_w, wT);
    k_prep_whh_h<<<dim3(512, 2), 256, 0, stream>>>(whh_f, whh_b, whhH);
    k_prep_wih<<<dim3(512, 2), 256, 0, stream>>>(wih_f, wih_b, wihT);
    k_prep_bias<<<dim3(4, 2), 256, 0, stream>>>(bih_f, bhh_f, bih_b, bhh_b, bias2);
    k_conv<<<dim3(NS / 8, NB), 128, 0, stream>>>(x, table, wT, conv_b, feat);
    k_xgate<<<dim3(NS * NB / 8, 2), 256, 0, stream>>>(feat, wihT, bias2, xg);
    k_lstm<<<dim3(64), 256, 0, stream>>>(whhH, xg, hcat);
    k_fc<<<dim3(NS * NB / 16), 256, 0, stream>>>(hcat, fc_w, fc_b, em);
    k_crf<<<dim3(NB), 64, 0, stream>>>(em, tags, mask, start_t, end_t, trans, res);
    k_final<<<dim3(1), 64, 0, stream>>>(res, (float*)d_out);
}